// Round 3
// baseline (31.638 us; speedup 1.0000x reference)
//
#include <hip/hip_runtime.h>

typedef __attribute__((ext_vector_type(8))) short short8;
typedef __attribute__((ext_vector_type(4))) float f32x4;
typedef __attribute__((ext_vector_type(4))) unsigned u32x4;

#define XSTR 72  // padded LDS row stride in bf16 elements (144 B)

__device__ __forceinline__ unsigned f2bf(float f) {
    unsigned u = __float_as_uint(f);
    return (u + 0x7fffu + ((u >> 16) & 1u)) >> 16;  // RNE float->bf16 bits
}
__device__ __forceinline__ unsigned pack2(float lo, float hi) {
    return f2bf(lo) | (f2bf(hi) << 16);
}

// ---- helpers -------------------------------------------------------------

// issue x-crop loads for one position (raw f32, stays in flight)
__device__ __forceinline__ void load_x(const float* __restrict__ x, int brow,
                                       int h, int w, int lh,
                                       f32x4 vr[2][2], f32x4 vi[2][2]) {
    const size_t gx = ((((size_t)brow * 2) * 64 + (16 + h)) * 64 + (16 + w)) * 64;
    const size_t gimg = (size_t)64 * 64 * 64;
    #pragma unroll
    for (int kk = 0; kk < 2; ++kk) {
        const int c0 = 32 * kk + 8 * lh;
        vr[kk][0] = *(const f32x4*)(x + gx + c0);
        vr[kk][1] = *(const f32x4*)(x + gx + c0 + 4);
        vi[kk][0] = *(const f32x4*)(x + gx + gimg + c0);
        vi[kk][1] = *(const f32x4*)(x + gx + gimg + c0 + 4);
    }
}

__device__ __forceinline__ void pack_x(const f32x4 vr[2][2], const f32x4 vi[2][2],
                                       u32x4 ar[2], u32x4 ai[2]) {
    #pragma unroll
    for (int kk = 0; kk < 2; ++kk)
        #pragma unroll
        for (int p = 0; p < 2; ++p) {
            ar[kk][2 * p]     = pack2(vr[kk][p][0], vr[kk][p][1]);
            ar[kk][2 * p + 1] = pack2(vr[kk][p][2], vr[kk][p][3]);
            ai[kk][2 * p]     = pack2(vi[kk][p][0], vi[kk][p][1]);
            ai[kk][2 * p + 1] = pack2(vi[kk][p][2], vi[kk][p][3]);
        }
}

__device__ __forceinline__ void load_W(const float* __restrict__ Wr,
                                       const float* __restrict__ Wi,
                                       int h, int w, int g, int cg,
                                       f32x4 rr[8], f32x4 ri[8]) {
    const size_t wbase = (((size_t)h * 32 + w) * 64) * 128;
    #pragma unroll
    for (int i = 0; i < 8; ++i) {
        size_t off = wbase + (size_t)(8 * cg + i) * 128 + 4 * g;
        rr[i] = *(const f32x4*)(Wr + off);
        ri[i] = *(const f32x4*)(Wi + off);
    }
}

// pack + transpose W regs into LDS [f][c] (bf16, padded rows)
__device__ __forceinline__ void pack_W(short* __restrict__ sWr, short* __restrict__ sWi,
                                       int g, int cg,
                                       const f32x4 rr[8], const f32x4 ri[8]) {
    #pragma unroll
    for (int j = 0; j < 4; ++j) {        // column f = 4g+j, c = 8cg..8cg+7
        u32x4 pr, pi;
        pr[0] = pack2(rr[0][j], rr[1][j]); pr[1] = pack2(rr[2][j], rr[3][j]);
        pr[2] = pack2(rr[4][j], rr[5][j]); pr[3] = pack2(rr[6][j], rr[7][j]);
        pi[0] = pack2(ri[0][j], ri[1][j]); pi[1] = pack2(ri[2][j], ri[3][j]);
        pi[2] = pack2(ri[4][j], ri[5][j]); pi[3] = pack2(ri[6][j], ri[7][j]);
        *(u32x4*)&sWr[(4 * g + j) * XSTR + 8 * cg] = pr;
        *(u32x4*)&sWi[(4 * g + j) * XSTR + 8 * cg] = pi;
    }
}

__device__ __forceinline__ void compute(const short* __restrict__ sWr,
                                        const short* __restrict__ sWi,
                                        const u32x4 ar[2], const u32x4 ai[2],
                                        int lr, int lh,
                                        f32x4 accR[8], f32x4 accI[8]) {
    #pragma unroll
    for (int ft = 0; ft < 8; ++ft)
        #pragma unroll
        for (int j = 0; j < 4; ++j) { accR[ft][j] = 0.f; accI[ft][j] = 0.f; }
    #pragma unroll
    for (int kk = 0; kk < 2; ++kk) {
        const int c0 = 32 * kk + 8 * lh;
        short8 arf = __builtin_bit_cast(short8, ar[kk]);
        short8 aif = __builtin_bit_cast(short8, ai[kk]);
        short8 anf;
        #pragma unroll
        for (int j = 0; j < 8; ++j) anf[j] = aif[j] ^ (short)0x8000;  // -xi
        #pragma unroll
        for (int ft = 0; ft < 8; ++ft) {
            short8 wr_ = *(const short8*)&sWr[(16 * ft + lr) * XSTR + c0];
            short8 wi_ = *(const short8*)&sWi[(16 * ft + lr) * XSTR + c0];
            accR[ft] = __builtin_amdgcn_mfma_f32_16x16x32_bf16(arf, wr_, accR[ft], 0, 0, 0);
            accR[ft] = __builtin_amdgcn_mfma_f32_16x16x32_bf16(anf, wi_, accR[ft], 0, 0, 0);
            accI[ft] = __builtin_amdgcn_mfma_f32_16x16x32_bf16(arf, wi_, accI[ft], 0, 0, 0);
            accI[ft] = __builtin_amdgcn_mfma_f32_16x16x32_bf16(aif, wr_, accI[ft], 0, 0, 0);
        }
    }
}

__device__ __forceinline__ void store_out(float* __restrict__ out,
                                          const f32x4 accR[8], const f32x4 accI[8],
                                          const float vbr[8], const float vbi[8],
                                          int h, int w, int wv, int lr, int lh) {
    #pragma unroll
    for (int ft = 0; ft < 8; ++ft) {
        const int fc = 16 * ft + lr;
        #pragma unroll
        for (int j = 0; j < 4; ++j) {
            const int b = 16 * wv + 4 * lh + j;
            size_t o = ((((size_t)b * 2) * 32 + h) * 32 + w) * 128 + fc;
            out[o] = fmaxf(accR[ft][j] + vbr[ft], 0.f);
            out[o + (size_t)32 * 32 * 128] = fmaxf(accI[ft][j] + vbi[ft], 0.f);
        }
    }
}

// x: (64,2,64,64,64) f32 ; W: (32,32,64,128) f32 ; out: (64,2,32,32,128) f32
// grid 512: block handles positions (h, 2q) and (h, 2q+1); W double-buffered in LDS.
__global__ __launch_bounds__(256, 2) void cplx_dot_kernel(
    const float* __restrict__ x, const float* __restrict__ Wr,
    const float* __restrict__ Wi, const float* __restrict__ br,
    const float* __restrict__ bi, float* __restrict__ out)
{
    __shared__ __align__(16) short sW[2][2][128 * XSTR];  // [buf][re/im]

    const int bid = blockIdx.x;          // 0..511
    const int h = bid >> 4, qw = bid & 15;
    const int w0 = 2 * qw, w1 = 2 * qw + 1;
    const int t = threadIdx.x;
    const int wv = t >> 6, l = t & 63;
    const int lr = l & 15, lh = l >> 4;
    const int g = t & 31, cg = t >> 5;
    const int brow = 16 * wv + lr;

    // bias (uniform across both positions)
    float vbr[8], vbi[8];
    #pragma unroll
    for (int ft = 0; ft < 8; ++ft) { vbr[ft] = br[16 * ft + lr]; vbi[ft] = bi[16 * ft + lr]; }

    // ---- position 0: load + stage ----
    f32x4 xr0[2][2], xi0[2][2];
    load_x(x, brow, h, w0, lh, xr0, xi0);
    f32x4 wr0[8], wi0[8];
    load_W(Wr, Wi, h, w0, g, cg, wr0, wi0);
    pack_W(&sW[0][0][0], &sW[0][1][0], g, cg, wr0, wi0);
    u32x4 ar0[2], ai0[2];
    pack_x(xr0, xi0, ar0, ai0);
    __syncthreads();

    // ---- issue position-1 loads (in flight during pos-0 compute+store) ----
    f32x4 xr1[2][2], xi1[2][2];
    load_x(x, brow, h, w1, lh, xr1, xi1);
    f32x4 wr1[8], wi1[8];
    load_W(Wr, Wi, h, w1, g, cg, wr1, wi1);

    // ---- compute + store position 0 ----
    f32x4 accR[8], accI[8];
    compute(&sW[0][0][0], &sW[0][1][0], ar0, ai0, lr, lh, accR, accI);
    store_out(out, accR, accI, vbr, vbi, h, w0, wv, lr, lh);

    // ---- stage position 1 (waits on its loads), compute + store ----
    pack_W(&sW[1][0][0], &sW[1][1][0], g, cg, wr1, wi1);
    u32x4 ar1[2], ai1[2];
    pack_x(xr1, xi1, ar1, ai1);
    __syncthreads();

    compute(&sW[1][0][0], &sW[1][1][0], ar1, ai1, lr, lh, accR, accI);
    store_out(out, accR, accI, vbr, vbi, h, w1, wv, lr, lh);
}

extern "C" void kernel_launch(void* const* d_in, const int* in_sizes, int n_in,
                              void* d_out, int out_size, void* d_ws, size_t ws_size,
                              hipStream_t stream) {
    const float* x  = (const float*)d_in[0];
    const float* Wr = (const float*)d_in[1];
    const float* Wi = (const float*)d_in[2];
    const float* br = (const float*)d_in[3];
    const float* bi = (const float*)d_in[4];
    float* out = (float*)d_out;
    hipLaunchKernelGGL(cplx_dot_kernel, dim3(512), dim3(256), 0, stream,
                       x, Wr, Wi, br, bi, out);
}